// Round 20
// baseline (371.086 us; speedup 1.0000x reference)
//
#include <hip/hip_runtime.h>
#include <hip/hip_fp16.h>
#include <math.h>

// GAT 3-layer: N=50000 nodes, E=800000 edges (+N self loops), HEADS=2, HID=64.
// R20 = R19 + (1) gemm row-tile 64->32 (grid 782->3128 blocks: R19 showed
// occupancy capped at 28% by blocks/CU=3, not LDS/VGPR) + (2) count_rank
// folded into the gemm1 launch as extra blocks (independent work; hides
// ~25us + one dispatch gap). Aggregate (R17 2dst/wave 2-edge) unchanged.

__device__ __forceinline__ float lrelu(float v) { return v > 0.f ? v : 0.2f * v; }

__device__ __forceinline__ float wave_max(float v) {
  for (int off = 32; off; off >>= 1) v = fmaxf(v, __shfl_xor(v, off, 64));
  return v;
}
__device__ __forceinline__ float half_sum(float v) {
  for (int off = 16; off; off >>= 1) v += __shfl_xor(v, off, 64);
  return v;
}
__device__ __forceinline__ float half_max(float v) {
  for (int off = 16; off; off >>= 1) v = fmaxf(v, __shfl_xor(v, off, 64));
  return v;
}

// ---- gemm body: 32 rows x 64 cols (head), 256 threads, 2x4 acc/thread.
// K-chunked LDS (32 x 68 floats = 8.7KB). H stored fp16; a_src/a_dst fp32.
template <int K>
__device__ __forceinline__ void gemm_body(
    int bx, int head, const float* __restrict__ X, const float* __restrict__ W,
    const float* __restrict__ asw, const float* __restrict__ adw,
    __half* __restrict__ H16, float* __restrict__ a_src,
    float* __restrict__ a_dst, int N, float* Xs) {
  int tid = threadIdx.x;
  int row0 = bx * 32;
  int cgrp = tid & 15;
  int rowid = tid >> 4;                 // 0..15, rows rowid*2, rowid*2+1
  int c0 = head * 64 + cgrp * 4;
  float acc[2][4] = {};

  for (int kc = 0; kc < K; kc += 64) {
    for (int idx = tid; idx < 32 * 64; idx += 256) {
      int r = idx >> 6;
      int k = idx & 63;
      int gr = row0 + r;
      if (gr >= N) gr = N - 1;        // clamp pad rows (stores are guarded)
      Xs[r * 68 + k] = X[(size_t)gr * K + kc + k];
    }
    __syncthreads();

    const float* wp = W + (size_t)kc * 128 + c0;
#pragma unroll 2
    for (int k = 0; k < 64; k += 4) {
      float4 xr[2];
#pragma unroll
      for (int j = 0; j < 2; ++j)
        xr[j] = *(const float4*)(&Xs[(rowid * 2 + j) * 68 + k]);
#pragma unroll
      for (int kk = 0; kk < 4; ++kk) {
        float4 w4 = *(const float4*)(wp + (k + kk) * 128);
#pragma unroll
        for (int j = 0; j < 2; ++j) {
          float xv = ((const float*)&xr[j])[kk];
          acc[j][0] = fmaf(xv, w4.x, acc[j][0]);
          acc[j][1] = fmaf(xv, w4.y, acc[j][1]);
          acc[j][2] = fmaf(xv, w4.z, acc[j][2]);
          acc[j][3] = fmaf(xv, w4.w, acc[j][3]);
        }
      }
    }
    __syncthreads();
  }

  float4 aw = *(const float4*)(asw + c0);
  float4 dw = *(const float4*)(adw + c0);
#pragma unroll
  for (int j = 0; j < 2; ++j) {
    int r = row0 + rowid * 2 + j;
    float sp = acc[j][0] * aw.x + acc[j][1] * aw.y + acc[j][2] * aw.z + acc[j][3] * aw.w;
    float dp = acc[j][0] * dw.x + acc[j][1] * dw.y + acc[j][2] * dw.z + acc[j][3] * dw.w;
#pragma unroll
    for (int off = 1; off < 16; off <<= 1) {
      sp += __shfl_xor(sp, off, 64);
      dp += __shfl_xor(dp, off, 64);
    }
    if (r < N) {
      union { __half2 h2[2]; uint2 u; } pk;
      pk.h2[0] = __floats2half2_rn(acc[j][0], acc[j][1]);
      pk.h2[1] = __floats2half2_rn(acc[j][2], acc[j][3]);
      *(uint2*)(H16 + (size_t)r * 128 + c0) = pk.u;
      if (cgrp == 0) {
        a_src[r * 2 + head] = sp;
        a_dst[r * 2 + head] = dp;
      }
    }
  }
}

// K1: blocks [0,GV): gemm layer-1; blocks [GV,GV+CV): count_rank
// (rank[j] = 0-based arrival order within dst; 4 indep atomics in flight).
__global__ __launch_bounds__(256) void k1_gemm_count(
    const float* __restrict__ X, const float* __restrict__ W,
    const float* __restrict__ asw, const float* __restrict__ adw,
    __half* __restrict__ H16, float* __restrict__ a_src,
    float* __restrict__ a_dst, const int* __restrict__ ei,
    int* __restrict__ deg, int* __restrict__ rank, int N, int E, int GV) {
  __shared__ float Xs[32 * 68];
  int bid = blockIdx.x;
  if (bid < GV) {
    gemm_body<128>(bid >> 1, bid & 1, X, W, asw, adw, H16, a_src, a_dst, N, Xs);
  } else {
    int j0 = (bid - GV) * 1024 + threadIdx.x;
#pragma unroll
    for (int k = 0; k < 4; ++k) {
      int j = j0 + k * 256;
      if (j < E) rank[j] = atomicAdd(&deg[ei[E + j]], 1);
    }
  }
}

// gemm layers 2/3: grid (nb32, 2)
template <int K>
__global__ __launch_bounds__(256) void gemm_kernel(
    const float* __restrict__ X, const float* __restrict__ W,
    const float* __restrict__ asw, const float* __restrict__ adw,
    __half* __restrict__ H16, float* __restrict__ a_src,
    float* __restrict__ a_dst, int N) {
  __shared__ float Xs[32 * 68];
  gemm_body<K>(blockIdx.x, blockIdx.y, X, W, asw, adw, H16, a_src, a_dst, N, Xs);
}

// ---- hierarchical exclusive scan over deg[0..n) (counts only) ----
__global__ void scan_blocks(const int* __restrict__ deg, int* __restrict__ row_ptr,
                            int* __restrict__ btot, int n) {
  __shared__ int sm[256];
  int i = blockIdx.x * 256 + threadIdx.x;
  int v = (i < n) ? deg[i] : 0;
  sm[threadIdx.x] = v;
  __syncthreads();
  for (int off = 1; off < 256; off <<= 1) {
    int t = (threadIdx.x >= off) ? sm[threadIdx.x - off] : 0;
    __syncthreads();
    sm[threadIdx.x] += t;
    __syncthreads();
  }
  if (i < n) row_ptr[i] = sm[threadIdx.x] - v;   // exclusive within block
  if (threadIdx.x == 255) btot[blockIdx.x] = sm[255];
}

__global__ void scan_totals(int* __restrict__ btot, int nb) {  // nb <= 256
  __shared__ int sm[256];
  int v = (threadIdx.x < nb) ? btot[threadIdx.x] : 0;
  sm[threadIdx.x] = v;
  __syncthreads();
  for (int off = 1; off < 256; off <<= 1) {
    int t = (threadIdx.x >= off) ? sm[threadIdx.x - off] : 0;
    __syncthreads();
    sm[threadIdx.x] += t;
    __syncthreads();
  }
  if (threadIdx.x < nb) btot[threadIdx.x] = sm[threadIdx.x] - v;  // exclusive
}

// row_ptr[i] = scan(counts) + i (reserves self-loop slot 0); drop self loop.
__global__ void scan_add(int* __restrict__ row_ptr, int* __restrict__ csr,
                         const int* __restrict__ btot, int n, int total) {
  int i = blockIdx.x * 256 + threadIdx.x;
  if (i < n) {
    int v = row_ptr[i] + btot[blockIdx.x] + i;
    row_ptr[i] = v;
    csr[v] = i;                         // self loop
  }
  if (i == 0) row_ptr[n] = total;
}

// no atomics: slot = row_ptr[dst] + 1 + rank. 4 independent edges per thread.
__global__ void place_kernel(const int* __restrict__ ei, const int* __restrict__ rank,
                             const int* __restrict__ row_ptr, int* __restrict__ csr,
                             int e) {
  int j0 = blockIdx.x * 1024 + threadIdx.x;
#pragma unroll
  for (int k = 0; k < 4; ++k) {
    int j = j0 + k * 256;
    if (j < e) {
      int d = ei[e + j];
      csr[row_ptr[d] + 1 + rank[j]] = ei[j];
    }
  }
}

// ---- 2-edges-per-load gather (R17). Lane (within half): sub = l32>>4 picks
// edge of pair, m = l32&15 -> 8 halves at c8 = m*8 (m<8: head0, m>=8: head1).
// Group g covers 8 edges via 4 loads (k): edge e = g*8 + k*2 + sub.
__device__ __forceinline__ void ld_grp8(const __half* __restrict__ H16, int half_,
                                        int c8, int headsel, int sub, int s,
                                        float p0, float p1, int g,
                                        uint4* h, float* q) {
#pragma unroll
  for (int k = 0; k < 4; ++k) {
    int idx = half_ + g * 8 + k * 2 + sub;   // e <= 31 always (g<=3)
    int st = __shfl(s, idx, 64);
    float q0 = __shfl(p0, idx, 64);
    float q1 = __shfl(p1, idx, 64);
    q[k] = headsel ? q1 : q0;
    h[k] = *(const uint4*)(H16 + (size_t)st * 128 + c8);
  }
}
__device__ __forceinline__ void fma_grp8(const uint4* h, const float* q,
                                         float* acc) {
#pragma unroll
  for (int k = 0; k < 4; ++k) {
    union { uint u; __half2 h2; } a, b, c, d;
    a.u = h[k].x; b.u = h[k].y; c.u = h[k].z; d.u = h[k].w;
    float2 f0 = __half22float2(a.h2);
    float2 f1 = __half22float2(b.h2);
    float2 f2 = __half22float2(c.h2);
    float2 f3 = __half22float2(d.h2);
    acc[0] = fmaf(f0.x, q[k], acc[0]);
    acc[1] = fmaf(f0.y, q[k], acc[1]);
    acc[2] = fmaf(f1.x, q[k], acc[2]);
    acc[3] = fmaf(f1.y, q[k], acc[3]);
    acc[4] = fmaf(f2.x, q[k], acc[4]);
    acc[5] = fmaf(f2.y, q[k], acc[5]);
    acc[6] = fmaf(f3.x, q[k], acc[6]);
    acc[7] = fmaf(f3.y, q[k], acc[7]);
  }
}
__device__ __forceinline__ void gather_pipe8(const __half* __restrict__ H16, int half_,
                                             int c8, int headsel, int sub, int s,
                                             float p0, float p1, int maxcnt,
                                             float* acc) {
  int groups = (maxcnt + 7) >> 3;   // 1..4 per 32-chunk
  uint4 ha[4], hb[4];
  float qa[4], qb[4];
  ld_grp8(H16, half_, c8, headsel, sub, s, p0, p1, 0, ha, qa);
  int g = 1;
  for (; g + 1 < groups; g += 2) {
    ld_grp8(H16, half_, c8, headsel, sub, s, p0, p1, g, hb, qb);
    fma_grp8(ha, qa, acc);
    ld_grp8(H16, half_, c8, headsel, sub, s, p0, p1, g + 1, ha, qa);
    fma_grp8(hb, qb, acc);
  }
  if (g < groups) {
    ld_grp8(H16, half_, c8, headsel, sub, s, p0, p1, g, hb, qb);
    fma_grp8(ha, qa, acc);
    fma_grp8(hb, qb, acc);
  } else {
    fma_grp8(ha, qa, acc);
  }
}

// Fused softmax + aggregate (R17). 2 dsts/wave (halves); within half, 2
// edges per load instruction. POOL=1: pv store into pvn.
template <int POOL>
__global__ __launch_bounds__(256) void aggregate_fused(
    const __half* __restrict__ H16, const float* __restrict__ a_src,
    const float* __restrict__ a_dst, const float* __restrict__ bias,
    const int* __restrict__ row_ptr, const int* __restrict__ csr,
    float* __restrict__ out, const float* __restrict__ lw,
    float* __restrict__ pvn, int N) {
  int lane = threadIdx.x & 63;
  int half_ = lane & 32;
  int l32 = lane & 31;
  int dst = blockIdx.x * 8 + ((threadIdx.x >> 6) << 1) + (half_ >> 5);
  bool live = dst < N;
  int beg = live ? row_ptr[dst] : 0;
  int end = live ? row_ptr[dst + 1] : 0;
  int cnt = end - beg;
  float2 ad = live ? ((const float2*)a_dst)[dst] : make_float2(0.f, 0.f);
  int sub = l32 >> 4;                   // edge-of-pair
  int m = l32 & 15;                     // 8-col group
  int c8 = m * 8;                       // halves offset (16B)
  int headsel = m >> 3;                 // m<8: head0 cols, m>=8: head1
  float acc[8] = {};
  float inv0, inv1;

  int maxcnt = (int)wave_max((float)cnt);
  if (maxcnt < 1) maxcnt = 1;

  if (maxcnt <= 32) {
    // ---- fast path: single 32-chunk per half ----
    int j = beg + l32;
    bool valid = l32 < cnt;
    int s = valid ? csr[j] : 0;
    float2 as = ((const float2*)a_src)[s];
    float e0 = valid ? lrelu(as.x + ad.x) : -1e30f;
    float e1 = valid ? lrelu(as.y + ad.y) : -1e30f;
    float m0 = half_max(e0);
    float m1 = half_max(e1);
    float p0 = __expf(e0 - m0);         // 0 for invalid lanes
    float p1 = __expf(e1 - m1);
    inv0 = 1.f / fmaxf(half_sum(valid ? p0 : 0.f), 1e-16f);
    inv1 = 1.f / fmaxf(half_sum(valid ? p1 : 0.f), 1e-16f);
    gather_pipe8(H16, half_, c8, headsel, sub, s, p0, p1, maxcnt, acc);
  } else {
    // ---- generic path: online softmax over 32-edge chunks per half ----
    float m0 = -1e30f, m1 = -1e30f, s0 = 0.f, s1 = 0.f;
    for (int base = 0; base < maxcnt; base += 32) {
      int j = beg + base + l32;
      bool valid = (base + l32) < cnt;
      int s = valid ? csr[j] : 0;
      float2 as = ((const float2*)a_src)[s];
      float e0 = valid ? lrelu(as.x + ad.x) : -1e30f;
      float e1 = valid ? lrelu(as.y + ad.y) : -1e30f;
      float nm0 = fmaxf(m0, half_max(e0));
      float nm1 = fmaxf(m1, half_max(e1));
      s0 = s0 * __expf(m0 - nm0) + half_sum(valid ? __expf(e0 - nm0) : 0.f);
      s1 = s1 * __expf(m1 - nm1) + half_sum(valid ? __expf(e1 - nm1) : 0.f);
      m0 = nm0; m1 = nm1;
    }
    inv0 = 1.f / fmaxf(s0, 1e-16f);
    inv1 = 1.f / fmaxf(s1, 1e-16f);
    for (int base = 0; base < maxcnt; base += 32) {
      int j = beg + base + l32;
      bool valid = (base + l32) < cnt;
      int s = valid ? csr[j] : 0;
      float2 as = ((const float2*)a_src)[s];
      float e0 = valid ? lrelu(as.x + ad.x) : -1e30f;
      float e1 = valid ? lrelu(as.y + ad.y) : -1e30f;
      float p0 = __expf(e0 - m0);       // 0 invalid
      float p1 = __expf(e1 - m1);
      int rem = maxcnt - base;
      if (rem > 32) rem = 32;
      gather_pipe8(H16, half_, c8, headsel, sub, s, p0, p1, rem, acc);
    }
  }

  // combine edge-of-pair partials: lanes sub=0/1 hold different edge subsets
#pragma unroll
  for (int j = 0; j < 8; ++j) acc[j] += __shfl_xor(acc[j], 16, 64);

  float il = headsel ? inv1 : inv0;
  float v[8], w[8];
#pragma unroll
  for (int j = 0; j < 8; ++j) v[j] = acc[j] * il;
#pragma unroll
  for (int j = 0; j < 8; ++j) w[j] = __shfl_xor(v[j], 8, 64);  // head pair

  if (m < 8 && sub == 0 && live) {
    int c = m * 8;
    float4 b0 = *(const float4*)(bias + c);
    float4 b1 = *(const float4*)(bias + c + 4);
    float r[8];
    r[0] = fmaxf(0.5f * (v[0] + w[0]) + b0.x, 0.f);
    r[1] = fmaxf(0.5f * (v[1] + w[1]) + b0.y, 0.f);
    r[2] = fmaxf(0.5f * (v[2] + w[2]) + b0.z, 0.f);
    r[3] = fmaxf(0.5f * (v[3] + w[3]) + b0.w, 0.f);
    r[4] = fmaxf(0.5f * (v[4] + w[4]) + b1.x, 0.f);
    r[5] = fmaxf(0.5f * (v[5] + w[5]) + b1.y, 0.f);
    r[6] = fmaxf(0.5f * (v[6] + w[6]) + b1.z, 0.f);
    r[7] = fmaxf(0.5f * (v[7] + w[7]) + b1.w, 0.f);
    if (POOL) {
      float4 l0 = *(const float4*)(lw + c);
      float4 l1 = *(const float4*)(lw + c + 4);
      float pv = r[0] * l0.x + r[1] * l0.y + r[2] * l0.z + r[3] * l0.w +
                 r[4] * l1.x + r[5] * l1.y + r[6] * l1.z + r[7] * l1.w;
      pv += __shfl_xor(pv, 1, 64);
      pv += __shfl_xor(pv, 2, 64);
      pv += __shfl_xor(pv, 4, 64);
      if (m == 0) pvn[dst] = pv;
    } else {
      *(float4*)(out + (size_t)dst * 64 + c) = make_float4(r[0], r[1], r[2], r[3]);
      *(float4*)(out + (size_t)dst * 64 + c + 4) = make_float4(r[4], r[5], r[6], r[7]);
    }
  }
}

__device__ __forceinline__ int lower_bound(const int* __restrict__ a, int n, int key) {
  int lo = 0, hi = n;
  while (lo < hi) {
    int mid = (lo + hi) >> 1;
    if (a[mid] < key) lo = mid + 1; else hi = mid;
  }
  return lo;
}

__global__ void finalize_kernel(const float* __restrict__ pvn,
                                const int* __restrict__ batch,
                                const float* __restrict__ lb,
                                float* __restrict__ out, int N, int G) {
  int g = blockIdx.x * blockDim.x + threadIdx.x;
  if (g >= G) return;
  int lo = lower_bound(batch, N, g);
  int hi = lower_bound(batch, N, g + 1);
  float s = 0.f;
  for (int i = lo; i < hi; ++i) s += pvn[i];
  out[g] = s / fmaxf((float)(hi - lo), 1.f) + lb[0];
}

extern "C" void kernel_launch(void* const* d_in, const int* in_sizes, int n_in,
                              void* d_out, int out_size, void* d_ws, size_t ws_size,
                              hipStream_t stream) {
  const float* x   = (const float*)d_in[0];
  const int* ei    = (const int*)d_in[1];
  const int* batch = (const int*)d_in[2];
  const float* W1  = (const float*)d_in[3];
  const float* as1 = (const float*)d_in[4];
  const float* ad1 = (const float*)d_in[5];
  const float* b1  = (const float*)d_in[6];
  const float* W2  = (const float*)d_in[7];
  const float* as2 = (const float*)d_in[8];
  const float* ad2 = (const float*)d_in[9];
  const float* b2  = (const float*)d_in[10];
  const float* W3  = (const float*)d_in[11];
  const float* as3 = (const float*)d_in[12];
  const float* ad3 = (const float*)d_in[13];
  const float* b3  = (const float*)d_in[14];
  const float* lw  = (const float*)d_in[15];
  const float* lb  = (const float*)d_in[16];
  float* out = (float*)d_out;

  const int N = in_sizes[0] / 128;   // 50000
  const int E = in_sizes[1] / 2;     // 800000
  const int ET = N + E;              // with self loops
  const int G = out_size;            // 2500
  const int NB = (N + 255) / 256;    // scan blocks (196 <= 256)

  char* p = (char*)d_ws;
  auto take = [&](size_t bytes) {
    char* r = p;
    p += (bytes + 255) & ~(size_t)255;
    return r;
  };
  int* deg      = (int*)take((size_t)N * 4);
  int* row_ptr  = (int*)take((size_t)(N + 1) * 4);
  int* rank     = (int*)take((size_t)E * 4);
  int* btot     = (int*)take((size_t)NB * 4);
  int* csr      = (int*)take((size_t)ET * 4);
  __half* H16   = (__half*)take((size_t)N * 128 * 2);
  float* a_src  = (float*)take((size_t)N * 2 * 4);
  float* a_dst  = (float*)take((size_t)N * 2 * 4);
  float* bufA   = (float*)take((size_t)N * 64 * 4);
  float* bufB   = (float*)take((size_t)N * 64 * 4);
  float* pvn    = (float*)take((size_t)N * 4);
  (void)ws_size; (void)n_in;

  const int nb32 = (N + 31) / 32;    // 1563 row tiles
  const int GV = nb32 * 2;           // gemm virtual blocks (x2 heads)
  const int CV = (E + 1023) / 1024;  // count_rank blocks
  const dim3 gblk2(nb32, 2);
  const int ablk = (N + 7) / 8;      // 8 dsts per block (2 per wave)

  // ---- CSR build start + layer-1 gemm (fused with count_rank) ----
  hipMemsetAsync(deg, 0, (size_t)N * 4, stream);
  k1_gemm_count<<<GV + CV, 256, 0, stream>>>(x, W1, as1, ad1, H16, a_src,
                                             a_dst, ei, deg, rank, N, E, GV);
  scan_blocks<<<NB, 256, 0, stream>>>(deg, row_ptr, btot, N);
  scan_totals<<<1, 256, 0, stream>>>(btot, NB);
  scan_add<<<NB, 256, 0, stream>>>(row_ptr, csr, btot, N, ET);
  place_kernel<<<(E + 1023) / 1024, 256, 0, stream>>>(ei, rank, row_ptr, csr, E);

  // ---- layer 1 aggregate ----
  aggregate_fused<0><<<ablk, 256, 0, stream>>>(H16, a_src, a_dst, b1, row_ptr, csr,
                                               bufA, lw, pvn, N);
  // ---- layer 2 ----
  gemm_kernel<64><<<gblk2, 256, 0, stream>>>(bufA, W2, as2, ad2, H16, a_src, a_dst, N);
  aggregate_fused<0><<<ablk, 256, 0, stream>>>(H16, a_src, a_dst, b2, row_ptr, csr,
                                               bufB, lw, pvn, N);
  // ---- layer 3 + fused pool ----
  gemm_kernel<64><<<gblk2, 256, 0, stream>>>(bufB, W3, as3, ad3, H16, a_src, a_dst, N);
  aggregate_fused<1><<<ablk, 256, 0, stream>>>(H16, a_src, a_dst, b3, row_ptr, csr,
                                               bufA, lw, pvn, N);

  // ---- finalize: per-graph mean + linear ----
  finalize_kernel<<<(G + 255) / 256, 256, 0, stream>>>(pvn, batch, lb, out, N, G);
}

// Round 21
// 347.468 us; speedup vs baseline: 1.0680x; 1.0680x over previous
//
#include <hip/hip_runtime.h>
#include <hip/hip_fp16.h>
#include <math.h>

// GAT 3-layer: N=50000 nodes, E=800000 edges (+N self loops), HEADS=2, HID=64.
// R21 = R17 verbatim (measured optimum, 349.3us). Session endpoint:
// - aggregate: fp16 H (fetch floor 194->85MB), 2 dsts/wave, 2-edges-per-load
//   512B instrs, 8-deep pipeline. Bracketing: R16 (1-edge) and R18
//   (4-edge/1-dst) both worse -> this is the gather optimum.
// - gemm1 ~43us: W-fetch-latency-floor (R18/R19/R20 occupancy levers all
//   neutral-or-worse). gemm2/3 ~20us each.
// - CSR: atomic-rank + scan + atomless place (R10); count_rank atomic-bound.
// - launch gaps ~90us: coop-kernel (R14), fused-dispatch (R15), gemm-fold
//   (R20) all failed to reclaim.

__device__ __forceinline__ float lrelu(float v) { return v > 0.f ? v : 0.2f * v; }

__device__ __forceinline__ float wave_max(float v) {
  for (int off = 32; off; off >>= 1) v = fmaxf(v, __shfl_xor(v, off, 64));
  return v;
}
__device__ __forceinline__ float half_sum(float v) {
  for (int off = 16; off; off >>= 1) v += __shfl_xor(v, off, 64);
  return v;
}
__device__ __forceinline__ float half_max(float v) {
  for (int off = 16; off; off >>= 1) v = fmaxf(v, __shfl_xor(v, off, 64));
  return v;
}

// rank[j] = 0-based arrival order within dst. 4 indep atomics in flight.
__global__ void count_rank(const int* __restrict__ ei, int* __restrict__ deg,
                           int* __restrict__ rank, int e) {
  int j0 = blockIdx.x * 1024 + threadIdx.x;
#pragma unroll
  for (int k = 0; k < 4; ++k) {
    int j = j0 + k * 256;
    if (j < e) rank[j] = atomicAdd(&deg[ei[e + j]], 1);
  }
}

// ---- hierarchical exclusive scan over deg[0..n) (counts only) ----
__global__ void scan_blocks(const int* __restrict__ deg, int* __restrict__ row_ptr,
                            int* __restrict__ btot, int n) {
  __shared__ int sm[256];
  int i = blockIdx.x * 256 + threadIdx.x;
  int v = (i < n) ? deg[i] : 0;
  sm[threadIdx.x] = v;
  __syncthreads();
  for (int off = 1; off < 256; off <<= 1) {
    int t = (threadIdx.x >= off) ? sm[threadIdx.x - off] : 0;
    __syncthreads();
    sm[threadIdx.x] += t;
    __syncthreads();
  }
  if (i < n) row_ptr[i] = sm[threadIdx.x] - v;   // exclusive within block
  if (threadIdx.x == 255) btot[blockIdx.x] = sm[255];
}

__global__ void scan_totals(int* __restrict__ btot, int nb) {  // nb <= 256
  __shared__ int sm[256];
  int v = (threadIdx.x < nb) ? btot[threadIdx.x] : 0;
  sm[threadIdx.x] = v;
  __syncthreads();
  for (int off = 1; off < 256; off <<= 1) {
    int t = (threadIdx.x >= off) ? sm[threadIdx.x - off] : 0;
    __syncthreads();
    sm[threadIdx.x] += t;
    __syncthreads();
  }
  if (threadIdx.x < nb) btot[threadIdx.x] = sm[threadIdx.x] - v;  // exclusive
}

// row_ptr[i] = scan(counts) + i (reserves self-loop slot 0); drop self loop.
__global__ void scan_add(int* __restrict__ row_ptr, int* __restrict__ csr,
                         const int* __restrict__ btot, int n, int total) {
  int i = blockIdx.x * 256 + threadIdx.x;
  if (i < n) {
    int v = row_ptr[i] + btot[blockIdx.x] + i;
    row_ptr[i] = v;
    csr[v] = i;                         // self loop
  }
  if (i == 0) row_ptr[n] = total;
}

// no atomics: slot = row_ptr[dst] + 1 + rank. 4 independent edges per thread.
__global__ void place_kernel(const int* __restrict__ ei, const int* __restrict__ rank,
                             const int* __restrict__ row_ptr, int* __restrict__ csr,
                             int e) {
  int j0 = blockIdx.x * 1024 + threadIdx.x;
#pragma unroll
  for (int k = 0; k < 4; ++k) {
    int j = j0 + k * 256;
    if (j < e) {
      int d = ei[e + j];
      csr[row_ptr[d] + 1 + rank[j]] = ei[j];
    }
  }
}

// Tiled gemm + fused attention reduce (R13 structure). H stored FP16:
// epilogue rounds acc to half4 (8B store). a_src/a_dst stay fp32 exact.
template <int K>
__global__ __launch_bounds__(256) void gemm_att(const float* __restrict__ X,
                                                const float* __restrict__ W,
                                                const float* __restrict__ asw,
                                                const float* __restrict__ adw,
                                                __half* __restrict__ H16,
                                                float* __restrict__ a_src,
                                                float* __restrict__ a_dst, int N) {
  __shared__ float Xs[64 * (K + 4)];
  int tid = threadIdx.x;
  int row0 = blockIdx.x * 64;
  int head = blockIdx.y;

  for (int idx = tid; idx < 64 * K; idx += 256) {
    int r = idx / K;
    int k = idx - r * K;
    int gr = row0 + r;
    if (gr >= N) gr = N - 1;          // clamp pad rows (stores are guarded)
    Xs[r * (K + 4) + k] = X[(size_t)gr * K + k];
  }
  __syncthreads();

  int cgrp = tid & 15;
  int rg = tid >> 4;
  int c0 = head * 64 + cgrp * 4;
  const float* wp = W + c0;
  float acc[4][4] = {};

#pragma unroll 2
  for (int k = 0; k < K; k += 4) {
    float4 xr[4];
#pragma unroll
    for (int j = 0; j < 4; ++j)
      xr[j] = *(const float4*)(&Xs[(rg * 4 + j) * (K + 4) + k]);
#pragma unroll
    for (int kk = 0; kk < 4; ++kk) {
      float4 w4 = *(const float4*)(wp + (k + kk) * 128);
#pragma unroll
      for (int j = 0; j < 4; ++j) {
        float xv = ((const float*)&xr[j])[kk];
        acc[j][0] = fmaf(xv, w4.x, acc[j][0]);
        acc[j][1] = fmaf(xv, w4.y, acc[j][1]);
        acc[j][2] = fmaf(xv, w4.z, acc[j][2]);
        acc[j][3] = fmaf(xv, w4.w, acc[j][3]);
      }
    }
  }

  float4 aw = *(const float4*)(asw + c0);
  float4 dw = *(const float4*)(adw + c0);
#pragma unroll
  for (int j = 0; j < 4; ++j) {
    int r = row0 + rg * 4 + j;
    float sp = acc[j][0] * aw.x + acc[j][1] * aw.y + acc[j][2] * aw.z + acc[j][3] * aw.w;
    float dp = acc[j][0] * dw.x + acc[j][1] * dw.y + acc[j][2] * dw.z + acc[j][3] * dw.w;
#pragma unroll
    for (int off = 1; off < 16; off <<= 1) {
      sp += __shfl_xor(sp, off, 64);
      dp += __shfl_xor(dp, off, 64);
    }
    if (r < N) {
      union { __half2 h2[2]; uint2 u; } pk;
      pk.h2[0] = __floats2half2_rn(acc[j][0], acc[j][1]);
      pk.h2[1] = __floats2half2_rn(acc[j][2], acc[j][3]);
      *(uint2*)(H16 + (size_t)r * 128 + c0) = pk.u;
      if (cgrp == 0) {
        a_src[r * 2 + head] = sp;
        a_dst[r * 2 + head] = dp;
      }
    }
  }
}

// ---- 2-edges-per-load gather. Lane (within half): sub = l32>>4 picks edge
// of pair, m = l32&15 -> 8 halves at c8 = m*8 (m<8: head0, m>=8: head1).
// Group g covers 8 edges via 4 loads (k): edge e = g*8 + k*2 + sub.
__device__ __forceinline__ void ld_grp8(const __half* __restrict__ H16, int half_,
                                        int c8, int headsel, int sub, int s,
                                        float p0, float p1, int g,
                                        uint4* h, float* q) {
#pragma unroll
  for (int k = 0; k < 4; ++k) {
    int idx = half_ + g * 8 + k * 2 + sub;   // e <= 31 always (g<=3)
    int st = __shfl(s, idx, 64);
    float q0 = __shfl(p0, idx, 64);
    float q1 = __shfl(p1, idx, 64);
    q[k] = headsel ? q1 : q0;
    h[k] = *(const uint4*)(H16 + (size_t)st * 128 + c8);
  }
}
__device__ __forceinline__ void fma_grp8(const uint4* h, const float* q,
                                         float* acc) {
#pragma unroll
  for (int k = 0; k < 4; ++k) {
    union { uint u; __half2 h2; } a, b, c, d;
    a.u = h[k].x; b.u = h[k].y; c.u = h[k].z; d.u = h[k].w;
    float2 f0 = __half22float2(a.h2);
    float2 f1 = __half22float2(b.h2);
    float2 f2 = __half22float2(c.h2);
    float2 f3 = __half22float2(d.h2);
    acc[0] = fmaf(f0.x, q[k], acc[0]);
    acc[1] = fmaf(f0.y, q[k], acc[1]);
    acc[2] = fmaf(f1.x, q[k], acc[2]);
    acc[3] = fmaf(f1.y, q[k], acc[3]);
    acc[4] = fmaf(f2.x, q[k], acc[4]);
    acc[5] = fmaf(f2.y, q[k], acc[5]);
    acc[6] = fmaf(f3.x, q[k], acc[6]);
    acc[7] = fmaf(f3.y, q[k], acc[7]);
  }
}
__device__ __forceinline__ void gather_pipe8(const __half* __restrict__ H16, int half_,
                                             int c8, int headsel, int sub, int s,
                                             float p0, float p1, int maxcnt,
                                             float* acc) {
  int groups = (maxcnt + 7) >> 3;   // 1..4 per 32-chunk
  uint4 ha[4], hb[4];
  float qa[4], qb[4];
  ld_grp8(H16, half_, c8, headsel, sub, s, p0, p1, 0, ha, qa);
  int g = 1;
  for (; g + 1 < groups; g += 2) {
    ld_grp8(H16, half_, c8, headsel, sub, s, p0, p1, g, hb, qb);
    fma_grp8(ha, qa, acc);
    ld_grp8(H16, half_, c8, headsel, sub, s, p0, p1, g + 1, ha, qa);
    fma_grp8(hb, qb, acc);
  }
  if (g < groups) {
    ld_grp8(H16, half_, c8, headsel, sub, s, p0, p1, g, hb, qb);
    fma_grp8(ha, qa, acc);
    fma_grp8(hb, qb, acc);
  } else {
    fma_grp8(ha, qa, acc);
  }
}

// Fused softmax + aggregate. 2 dsts/wave (halves); within half, 2 edges per
// load instruction. POOL=1: pv store into pvn.
template <int POOL>
__global__ __launch_bounds__(256) void aggregate_fused(
    const __half* __restrict__ H16, const float* __restrict__ a_src,
    const float* __restrict__ a_dst, const float* __restrict__ bias,
    const int* __restrict__ row_ptr, const int* __restrict__ csr,
    float* __restrict__ out, const float* __restrict__ lw,
    float* __restrict__ pvn, int N) {
  int lane = threadIdx.x & 63;
  int half_ = lane & 32;
  int l32 = lane & 31;
  int dst = blockIdx.x * 8 + ((threadIdx.x >> 6) << 1) + (half_ >> 5);
  bool live = dst < N;
  int beg = live ? row_ptr[dst] : 0;
  int end = live ? row_ptr[dst + 1] : 0;
  int cnt = end - beg;
  float2 ad = live ? ((const float2*)a_dst)[dst] : make_float2(0.f, 0.f);
  int sub = l32 >> 4;                   // edge-of-pair
  int m = l32 & 15;                     // 8-col group
  int c8 = m * 8;                       // halves offset (16B)
  int headsel = m >> 3;                 // m<8: head0 cols, m>=8: head1
  float acc[8] = {};
  float inv0, inv1;

  int maxcnt = (int)wave_max((float)cnt);
  if (maxcnt < 1) maxcnt = 1;

  if (maxcnt <= 32) {
    // ---- fast path: single 32-chunk per half ----
    int j = beg + l32;
    bool valid = l32 < cnt;
    int s = valid ? csr[j] : 0;
    float2 as = ((const float2*)a_src)[s];
    float e0 = valid ? lrelu(as.x + ad.x) : -1e30f;
    float e1 = valid ? lrelu(as.y + ad.y) : -1e30f;
    float m0 = half_max(e0);
    float m1 = half_max(e1);
    float p0 = __expf(e0 - m0);         // 0 for invalid lanes
    float p1 = __expf(e1 - m1);
    inv0 = 1.f / fmaxf(half_sum(valid ? p0 : 0.f), 1e-16f);
    inv1 = 1.f / fmaxf(half_sum(valid ? p1 : 0.f), 1e-16f);
    gather_pipe8(H16, half_, c8, headsel, sub, s, p0, p1, maxcnt, acc);
  } else {
    // ---- generic path: online softmax over 32-edge chunks per half ----
    float m0 = -1e30f, m1 = -1e30f, s0 = 0.f, s1 = 0.f;
    for (int base = 0; base < maxcnt; base += 32) {
      int j = beg + base + l32;
      bool valid = (base + l32) < cnt;
      int s = valid ? csr[j] : 0;
      float2 as = ((const float2*)a_src)[s];
      float e0 = valid ? lrelu(as.x + ad.x) : -1e30f;
      float e1 = valid ? lrelu(as.y + ad.y) : -1e30f;
      float nm0 = fmaxf(m0, half_max(e0));
      float nm1 = fmaxf(m1, half_max(e1));
      s0 = s0 * __expf(m0 - nm0) + half_sum(valid ? __expf(e0 - nm0) : 0.f);
      s1 = s1 * __expf(m1 - nm1) + half_sum(valid ? __expf(e1 - nm1) : 0.f);
      m0 = nm0; m1 = nm1;
    }
    inv0 = 1.f / fmaxf(s0, 1e-16f);
    inv1 = 1.f / fmaxf(s1, 1e-16f);
    for (int base = 0; base < maxcnt; base += 32) {
      int j = beg + base + l32;
      bool valid = (base + l32) < cnt;
      int s = valid ? csr[j] : 0;
      float2 as = ((const float2*)a_src)[s];
      float e0 = valid ? lrelu(as.x + ad.x) : -1e30f;
      float e1 = valid ? lrelu(as.y + ad.y) : -1e30f;
      float p0 = __expf(e0 - m0);       // 0 invalid
      float p1 = __expf(e1 - m1);
      int rem = maxcnt - base;
      if (rem > 32) rem = 32;
      gather_pipe8(H16, half_, c8, headsel, sub, s, p0, p1, rem, acc);
    }
  }

  // combine edge-of-pair partials: lanes sub=0/1 hold different edge subsets
#pragma unroll
  for (int j = 0; j < 8; ++j) acc[j] += __shfl_xor(acc[j], 16, 64);

  float il = headsel ? inv1 : inv0;
  float v[8], w[8];
#pragma unroll
  for (int j = 0; j < 8; ++j) v[j] = acc[j] * il;
#pragma unroll
  for (int j = 0; j < 8; ++j) w[j] = __shfl_xor(v[j], 8, 64);  // head pair

  if (m < 8 && sub == 0 && live) {
    int c = m * 8;
    float4 b0 = *(const float4*)(bias + c);
    float4 b1 = *(const float4*)(bias + c + 4);
    float r[8];
    r[0] = fmaxf(0.5f * (v[0] + w[0]) + b0.x, 0.f);
    r[1] = fmaxf(0.5f * (v[1] + w[1]) + b0.y, 0.f);
    r[2] = fmaxf(0.5f * (v[2] + w[2]) + b0.z, 0.f);
    r[3] = fmaxf(0.5f * (v[3] + w[3]) + b0.w, 0.f);
    r[4] = fmaxf(0.5f * (v[4] + w[4]) + b1.x, 0.f);
    r[5] = fmaxf(0.5f * (v[5] + w[5]) + b1.y, 0.f);
    r[6] = fmaxf(0.5f * (v[6] + w[6]) + b1.z, 0.f);
    r[7] = fmaxf(0.5f * (v[7] + w[7]) + b1.w, 0.f);
    if (POOL) {
      float4 l0 = *(const float4*)(lw + c);
      float4 l1 = *(const float4*)(lw + c + 4);
      float pv = r[0] * l0.x + r[1] * l0.y + r[2] * l0.z + r[3] * l0.w +
                 r[4] * l1.x + r[5] * l1.y + r[6] * l1.z + r[7] * l1.w;
      pv += __shfl_xor(pv, 1, 64);
      pv += __shfl_xor(pv, 2, 64);
      pv += __shfl_xor(pv, 4, 64);
      if (m == 0) pvn[dst] = pv;
    } else {
      *(float4*)(out + (size_t)dst * 64 + c) = make_float4(r[0], r[1], r[2], r[3]);
      *(float4*)(out + (size_t)dst * 64 + c + 4) = make_float4(r[4], r[5], r[6], r[7]);
    }
  }
}

__device__ __forceinline__ int lower_bound(const int* __restrict__ a, int n, int key) {
  int lo = 0, hi = n;
  while (lo < hi) {
    int mid = (lo + hi) >> 1;
    if (a[mid] < key) lo = mid + 1; else hi = mid;
  }
  return lo;
}

__global__ void finalize_kernel(const float* __restrict__ pvn,
                                const int* __restrict__ batch,
                                const float* __restrict__ lb,
                                float* __restrict__ out, int N, int G) {
  int g = blockIdx.x * blockDim.x + threadIdx.x;
  if (g >= G) return;
  int lo = lower_bound(batch, N, g);
  int hi = lower_bound(batch, N, g + 1);
  float s = 0.f;
  for (int i = lo; i < hi; ++i) s += pvn[i];
  out[g] = s / fmaxf((float)(hi - lo), 1.f) + lb[0];
}

extern "C" void kernel_launch(void* const* d_in, const int* in_sizes, int n_in,
                              void* d_out, int out_size, void* d_ws, size_t ws_size,
                              hipStream_t stream) {
  const float* x   = (const float*)d_in[0];
  const int* ei    = (const int*)d_in[1];
  const int* batch = (const int*)d_in[2];
  const float* W1  = (const float*)d_in[3];
  const float* as1 = (const float*)d_in[4];
  const float* ad1 = (const float*)d_in[5];
  const float* b1  = (const float*)d_in[6];
  const float* W2  = (const float*)d_in[7];
  const float* as2 = (const float*)d_in[8];
  const float* ad2 = (const float*)d_in[9];
  const float* b2  = (const float*)d_in[10];
  const float* W3  = (const float*)d_in[11];
  const float* as3 = (const float*)d_in[12];
  const float* ad3 = (const float*)d_in[13];
  const float* b3  = (const float*)d_in[14];
  const float* lw  = (const float*)d_in[15];
  const float* lb  = (const float*)d_in[16];
  float* out = (float*)d_out;

  const int N = in_sizes[0] / 128;   // 50000
  const int E = in_sizes[1] / 2;     // 800000
  const int ET = N + E;              // with self loops
  const int G = out_size;            // 2500
  const int NB = (N + 255) / 256;    // scan blocks (196 <= 256)

  char* p = (char*)d_ws;
  auto take = [&](size_t bytes) {
    char* r = p;
    p += (bytes + 255) & ~(size_t)255;
    return r;
  };
  int* deg      = (int*)take((size_t)N * 4);
  int* row_ptr  = (int*)take((size_t)(N + 1) * 4);
  int* rank     = (int*)take((size_t)E * 4);
  int* btot     = (int*)take((size_t)NB * 4);
  int* csr      = (int*)take((size_t)ET * 4);
  __half* H16   = (__half*)take((size_t)N * 128 * 2);
  float* a_src  = (float*)take((size_t)N * 2 * 4);
  float* a_dst  = (float*)take((size_t)N * 2 * 4);
  float* bufA   = (float*)take((size_t)N * 64 * 4);
  float* bufB   = (float*)take((size_t)N * 64 * 4);
  float* pvn    = (float*)take((size_t)N * 4);
  (void)ws_size; (void)n_in;

  // ---- CSR build (dst-grouped, with self loops) ----
  hipMemsetAsync(deg, 0, (size_t)N * 4, stream);
  count_rank<<<(E + 1023) / 1024, 256, 0, stream>>>(ei, deg, rank, E);
  scan_blocks<<<NB, 256, 0, stream>>>(deg, row_ptr, btot, N);
  scan_totals<<<1, 256, 0, stream>>>(btot, NB);
  scan_add<<<NB, 256, 0, stream>>>(row_ptr, csr, btot, N, ET);
  place_kernel<<<(E + 1023) / 1024, 256, 0, stream>>>(ei, rank, row_ptr, csr, E);

  const dim3 gblk((N + 63) / 64, 2);
  const int ablk = (N + 7) / 8;   // 8 dsts per block (2 per wave)

  // ---- layer 1 (K=128) ----
  gemm_att<128><<<gblk, 256, 0, stream>>>(x, W1, as1, ad1, H16, a_src, a_dst, N);
  aggregate_fused<0><<<ablk, 256, 0, stream>>>(H16, a_src, a_dst, b1, row_ptr, csr,
                                               bufA, lw, pvn, N);
  // ---- layer 2 (K=64) ----
  gemm_att<64><<<gblk, 256, 0, stream>>>(bufA, W2, as2, ad2, H16, a_src, a_dst, N);
  aggregate_fused<0><<<ablk, 256, 0, stream>>>(H16, a_src, a_dst, b2, row_ptr, csr,
                                               bufB, lw, pvn, N);
  // ---- layer 3 (K=64) + fused pool ----
  gemm_att<64><<<gblk, 256, 0, stream>>>(bufB, W3, as3, ad3, H16, a_src, a_dst, N);
  aggregate_fused<1><<<ablk, 256, 0, stream>>>(H16, a_src, a_dst, b3, row_ptr, csr,
                                               bufA, lw, pvn, N);

  // ---- finalize: per-graph mean + linear ----
  finalize_kernel<<<(G + 255) / 256, 256, 0, stream>>>(pvn, batch, lb, out, N, G);
}